// Round 9
// baseline (52.898 us; speedup 1.0000x reference)
//
#include <hip/hip_runtime.h>
#include <math.h>

// WaveletLayerND: fused mexican-hat wavelet + grouped 3x3 conv (kernel 1),
// then 1x1 channel mix (kernel 2). B=4, O=I=32, H=W=128, fp32 throughout.
//
// Round 9: 2-channel ILP on the r8 straight-line skeleton. Model from r8
// counters: per-SIMD issue 27%, per-wave chain ~190cy/row (psi ~30 -> bperm
// ~120 -> 9 dependent acc FMAs ~36) with ~2 resident waves/SIMD. Two
// independent channel streams per wave double issue density and let the two
// bperm pairs cover each other; acc is shared (sum over channels). No extra
// loads or psi vs 1-channel. Natural VGPR (~72); NO launch_bounds cap
// (r7: capping below natural footprint spills to scratch).

#define RSTRIP 8   // output rows per wave

typedef float v2f __attribute__((ext_vector_type(2)));

static __device__ __forceinline__ v2f vfma(float w, v2f a, v2f c) {
  return __builtin_elementwise_fma(a, (v2f){w, w}, c);
}
static __device__ __forceinline__ float bperm(int addr, float v) {
  return __int_as_float(__builtin_amdgcn_ds_bpermute(addr, __float_as_int(v)));
}

struct PsiRow { v2f L, C, R; };

// psi + horizontal halo for one row of one channel.
// L={psi(c0-1),psi(c0)}, C={psi(c0),psi(c0+1)}, R={psi(c0+1),psi(c0+2)}
static __device__ __forceinline__ PsiRow mkpsi(v2f xv, float rv, float rs,
                                               float trs, float mhc,
                                               int a_up, int a_dn,
                                               bool lane0, bool lane63) {
  const float NHL2E = -0.72134752044448170f; // -0.5 * log2(e)
  const v2f sx = __builtin_elementwise_fma(xv, (v2f){rs, rs}, (v2f){-trs, -trs});
  const v2f u  = sx * sx;
  v2f e;
  e.x = __builtin_amdgcn_exp2f(u.x * NHL2E);
  e.y = __builtin_amdgcn_exp2f(u.y * NHL2E);
  v2f p = __builtin_elementwise_fma(u, (v2f){mhc, mhc}, (v2f){-mhc, -mhc}) * e;
  p = p * (v2f){rv, rv};                     // row validity == zero padding
  float pl = bperm(a_up, p.y);
  float pr = bperm(a_dn, p.x);
  if (lane0)  pl = 0.f;
  if (lane63) pr = 0.f;
  PsiRow o;
  o.L = (v2f){pl, p.x};
  o.C = p;
  o.R = (v2f){p.y, pr};
  return o;
}

#define LDROW(base, r) (*(const v2f*)((base) + (size_t)(min(max((r), 0), 127)) * 128))

__global__ __launch_bounds__(256) void wavelet_grouped_conv(
    const float* __restrict__ x,      // (B, I, H, W)
    const float* __restrict__ scale,  // (O*I)
    const float* __restrict__ trans,  // (O*I)
    const float* __restrict__ wconv,  // (O, I, 3, 3)
    float* __restrict__ y,            // (B, O, H, W) workspace
    float mhc)
{
  const int tid   = threadIdx.x;
  const int lane  = tid & 63;
  const int iq    = tid >> 6;          // 0..3: which i-quarter this wave owns
  const int strip = blockIdx.x;        // 0..15
  const int o     = blockIdx.y;        // 0..31
  const int b     = blockIdx.z;        // 0..3
  const int r0    = strip * RSTRIP;
  const int c0    = lane << 1;         // this thread's two columns

  // hoisted bpermute byte-addresses: lane-1 and lane+1 (mod 64)
  const int a_up = ((lane + 63) & 63) << 2;
  const int a_dn = ((lane +  1) & 63) << 2;
  const bool lane0  = (lane == 0);
  const bool lane63 = (lane == 63);

  // row-validity factors (top halo row / bottom rows outside the image)
  const float rvm1 = (r0 > 0)       ? 1.f : 0.f;   // row r0-1
  const float rv8  = (r0 + 8 < 128) ? 1.f : 0.f;   // row r0+8

  v2f acc[RSTRIP];
#pragma unroll
  for (int r = 0; r < RSTRIP; ++r) acc[r] = (v2f){0.f, 0.f};

  const float* xb = x + (size_t)b * 32 * 128 * 128;

#pragma unroll 1
  for (int ii = 0; ii < 4; ++ii) {
    const int iA  = iq * 8 + ii * 2;            // wave-uniform
    const int oiA = __builtin_amdgcn_readfirstlane(o * 32 + iA);
    const int oiB = oiA + 1;
    const float rsA  = 1.0f / scale[oiA];
    const float trsA = trans[oiA] * rsA;
    const float rsB  = 1.0f / scale[oiB];
    const float trsB = trans[oiB] * rsB;
    const float* wpA = wconv + oiA * 9;
    const float A00 = wpA[0], A01 = wpA[1], A02 = wpA[2];
    const float A10 = wpA[3], A11 = wpA[4], A12 = wpA[5];
    const float A20 = wpA[6], A21 = wpA[7], A22 = wpA[8];
    const float* wpB = wconv + oiB * 9;
    const float B00 = wpB[0], B01 = wpB[1], B02 = wpB[2];
    const float B10 = wpB[3], B11 = wpB[4], B12 = wpB[5];
    const float B20 = wpB[6], B21 = wpB[7], B22 = wpB[8];
    const float* baseA = xb + (size_t)iA * 128 * 128 + c0;
    const float* baseB = baseA + 128 * 128;

    // prologue: rows r0-1, r0 through psi; prefetch rows r0+1, r0+2
    v2f xCA, xDA, xCB, xDB;
    PsiRow mA, cA, mB, cB;
    {
      const v2f x0A = LDROW(baseA, r0 - 1);
      const v2f x0B = LDROW(baseB, r0 - 1);
      const v2f x1A = LDROW(baseA, r0);
      const v2f x1B = LDROW(baseB, r0);
      xCA = LDROW(baseA, r0 + 1);
      xCB = LDROW(baseB, r0 + 1);
      xDA = LDROW(baseA, r0 + 2);
      xDB = LDROW(baseB, r0 + 2);
      mA = mkpsi(x0A, rvm1, rsA, trsA, mhc, a_up, a_dn, lane0, lane63);
      mB = mkpsi(x0B, rvm1, rsB, trsB, mhc, a_up, a_dn, lane0, lane63);
      cA = mkpsi(x1A, 1.f,  rsA, trsA, mhc, a_up, a_dn, lane0, lane63);
      cB = mkpsi(x1B, 1.f,  rsB, trsB, mhc, a_up, a_dn, lane0, lane63);
    }

#pragma unroll
    for (int r = 0; r < RSTRIP; ++r) {
      const v2f xEA = LDROW(baseA, r0 + r + 3);   // lookahead-2
      const v2f xEB = LDROW(baseB, r0 + r + 3);
      const float rvn = (r == RSTRIP - 1) ? rv8 : 1.f;
      const PsiRow nA = mkpsi(xCA, rvn, rsA, trsA, mhc, a_up, a_dn, lane0, lane63);
      const PsiRow nB = mkpsi(xCB, rvn, rsB, trsB, mhc, a_up, a_dn, lane0, lane63);
      v2f a = acc[r];
      a = vfma(A00, mA.L, a); a = vfma(A01, mA.C, a); a = vfma(A02, mA.R, a);
      a = vfma(B00, mB.L, a); a = vfma(B01, mB.C, a); a = vfma(B02, mB.R, a);
      a = vfma(A10, cA.L, a); a = vfma(A11, cA.C, a); a = vfma(A12, cA.R, a);
      a = vfma(B10, cB.L, a); a = vfma(B11, cB.C, a); a = vfma(B12, cB.R, a);
      a = vfma(A20, nA.L, a); a = vfma(A21, nA.C, a); a = vfma(A22, nA.R, a);
      a = vfma(B20, nB.L, a); a = vfma(B21, nB.C, a); a = vfma(B22, nB.R, a);
      acc[r] = a;
      mA = cA; cA = nA; xCA = xDA; xDA = xEA;
      mB = cB; cB = nB; xCB = xDB; xDB = xEB;
    }
  }

  // reduce the four i-quarters through LDS (lane-major; b64 2-way is free)
  __shared__ v2f red[3][RSTRIP][64];   // 12 KB
  if (iq != 0) {
#pragma unroll
    for (int r = 0; r < RSTRIP; ++r) red[iq - 1][r][lane] = acc[r];
  }
  __syncthreads();
  if (iq == 0) {
    float* yb = y + (((size_t)b * 32 + o) * 128 + r0) * 128 + c0;
#pragma unroll
    for (int r = 0; r < RSTRIP; ++r) {
      const v2f v = acc[r] + red[0][r][lane] + red[1][r][lane] + red[2][r][lane];
      *(v2f*)(yb + (size_t)r * 128) = v;
    }
  }
}

__global__ __launch_bounds__(256) void mix1x1(
    const float* __restrict__ y,    // (B, O, H*W)
    const float* __restrict__ fw,   // (O_out, O_in)
    float* __restrict__ out)        // (B, O, H*W)
{
  const int px = blockIdx.x * 256 + threadIdx.x;  // 0..16383
  const int b  = blockIdx.y;
  const float* yb = y + (size_t)b * 32 * 16384 + px;
  float v[32];
#pragma unroll
  for (int o = 0; o < 32; ++o) v[o] = yb[(size_t)o * 16384];
  float* ob = out + (size_t)b * 32 * 16384 + px;
#pragma unroll
  for (int p = 0; p < 32; ++p) {
    float a = 0.f;
#pragma unroll
    for (int o = 0; o < 32; ++o) a = fmaf(fw[p * 32 + o], v[o], a);
    ob[(size_t)p * 16384] = a;
  }
}

extern "C" void kernel_launch(void* const* d_in, const int* in_sizes, int n_in,
                              void* d_out, int out_size, void* d_ws, size_t ws_size,
                              hipStream_t stream) {
  const float* x     = (const float*)d_in[0];
  const float* scale = (const float*)d_in[1];
  const float* trans = (const float*)d_in[2];
  const float* wconv = (const float*)d_in[3];
  const float* fw    = (const float*)d_in[4];
  float* out = (float*)d_out;
  float* y   = (float*)d_ws;   // 4*32*128*128 floats = 8.39 MB

  const float mhc = (float)(2.0 / (sqrt(3.0) * pow(M_PI, 0.25)));

  dim3 g1(128 / RSTRIP, 32, 4);  // (strips, o, b) = 2048 blocks x 256 thr
  wavelet_grouped_conv<<<g1, 256, 0, stream>>>(x, scale, trans, wconv, y, mhc);

  dim3 g2(16384 / 256, 4);       // (pixel tiles, b)
  mix1x1<<<g2, 256, 0, stream>>>(y, fw, out);
}

// Round 10
// 46.041 us; speedup vs baseline: 1.1489x; 1.1489x over previous
//
#include <hip/hip_runtime.h>
#include <math.h>

// WaveletLayerND: fused mexican-hat wavelet + grouped 3x3 conv (kernel 1),
// then 1x1 channel mix (kernel 2). B=4, O=I=32, H=W=128, fp32 throughout.
//
// Round 10: tap-basis accumulation. The halo exchange commutes with the
// channel sum, so the hot loop accumulates per-tap sums
//   TL/TC/TR[r] += w{k0,k1,k2} * psi   (9 pk_fma per input row, no halo)
// and the lane-shift combine out[c]=TL[c-1]+TC[c]+TR[c+1] happens ONCE per
// output row at the end (2 bperm x 8 rows) instead of twice per psi-row
// (160). Removes the ~120cy ds_bpermute dependency from the hot loop; rows
// are fully independent (no rolling window). Natural VGPR (~64-72); NO
// launch_bounds cap (r7: capping below natural footprint -> scratch spill).

#define RSTRIP 8   // output rows per wave

typedef float v2f __attribute__((ext_vector_type(2)));

static __device__ __forceinline__ v2f vfma(float w, v2f a, v2f c) {
  return __builtin_elementwise_fma(a, (v2f){w, w}, c);
}
static __device__ __forceinline__ float bperm(int addr, float v) {
  return __int_as_float(__builtin_amdgcn_ds_bpermute(addr, __float_as_int(v)));
}

#define LDROW(base, r) (*(const v2f*)((base) + (size_t)(min(max((r), 0), 127)) * 128))

__global__ __launch_bounds__(256) void wavelet_grouped_conv(
    const float* __restrict__ x,      // (B, I, H, W)
    const float* __restrict__ scale,  // (O*I)
    const float* __restrict__ trans,  // (O*I)
    const float* __restrict__ wconv,  // (O, I, 3, 3)
    float* __restrict__ y,            // (B, O, H, W) workspace
    float mhc)
{
  const int tid   = threadIdx.x;
  const int lane  = tid & 63;
  const int iq    = tid >> 6;          // 0..3: which i-quarter this wave owns
  const int strip = blockIdx.x;        // 0..15
  const int o     = blockIdx.y;        // 0..31
  const int b     = blockIdx.z;        // 0..3
  const int r0    = strip * RSTRIP;
  const int c0    = lane << 1;         // this thread's two columns

  // bpermute byte-addresses: lane-1 and lane+1 (mod 64) — epilogue only
  const int a_up = ((lane + 63) & 63) << 2;
  const int a_dn = ((lane +  1) & 63) << 2;
  const bool lane0  = (lane == 0);
  const bool lane63 = (lane == 63);

  // row-validity factors (top halo row / bottom halo row vs image edge)
  const float rvm1 = (r0 > 0)       ? 1.f : 0.f;   // input row r0-1
  const float rv8  = (r0 + 8 < 128) ? 1.f : 0.f;   // input row r0+8

  const float NHL2E = -0.72134752044448170f; // -0.5 * log2(e)

  // per-tap accumulators: out[c] = TL[c-1] + TC[c] + TR[c+1] (combined at end)
  v2f TL[RSTRIP], TC[RSTRIP], TR[RSTRIP];
#pragma unroll
  for (int r = 0; r < RSTRIP; ++r) {
    TL[r] = (v2f){0.f, 0.f}; TC[r] = (v2f){0.f, 0.f}; TR[r] = (v2f){0.f, 0.f};
  }

  const float* xb = x + (size_t)b * 32 * 128 * 128;

#pragma unroll 1
  for (int ii = 0; ii < 8; ++ii) {
    const int i0 = iq * 8 + ii;                 // wave-uniform
    const int oi = __builtin_amdgcn_readfirstlane(o * 32 + i0);
    const float rs  = 1.0f / scale[oi];
    const float trs = trans[oi] * rs;
    const float* wp = wconv + oi * 9;
    const float w00 = wp[0], w01 = wp[1], w02 = wp[2];
    const float w10 = wp[3], w11 = wp[4], w12 = wp[5];
    const float w20 = wp[6], w21 = wp[7], w22 = wp[8];
    const float* base = xb + (size_t)i0 * 128 * 128 + c0;

    v2f xa = LDROW(base, r0 - 1);     // row for j=0
    v2f xbv = LDROW(base, r0);        // row for j=1

#pragma unroll
    for (int j = 0; j < RSTRIP + 2; ++j) {
      const v2f xc = LDROW(base, r0 + j + 1);   // lookahead-2 (clamped)
      const float rv = (j == 0) ? rvm1 : (j == RSTRIP + 1) ? rv8 : 1.f;
      // psi((x-t)/s) = MH_C*(u-1)*exp(-u/2), u = sx^2  — packed
      const v2f sx = __builtin_elementwise_fma(xa, (v2f){rs, rs},
                                               (v2f){-trs, -trs});
      const v2f u  = sx * sx;
      v2f e;
      e.x = __builtin_amdgcn_exp2f(u.x * NHL2E);
      e.y = __builtin_amdgcn_exp2f(u.y * NHL2E);
      v2f p = __builtin_elementwise_fma(u, (v2f){mhc, mhc},
                                        (v2f){-mhc, -mhc}) * e;
      p = p * (v2f){rv, rv};          // row validity == zero padding

      // input row ir=r0+j-1 feeds out rows t=j (w0x), t=j-1 (w1x), t=j-2 (w2x)
      if (j <= RSTRIP - 1) {
        TL[j] = vfma(w00, p, TL[j]);
        TC[j] = vfma(w01, p, TC[j]);
        TR[j] = vfma(w02, p, TR[j]);
      }
      if (j >= 1 && j <= RSTRIP) {
        TL[j-1] = vfma(w10, p, TL[j-1]);
        TC[j-1] = vfma(w11, p, TC[j-1]);
        TR[j-1] = vfma(w12, p, TR[j-1]);
      }
      if (j >= 2) {
        TL[j-2] = vfma(w20, p, TL[j-2]);
        TC[j-2] = vfma(w21, p, TC[j-2]);
        TR[j-2] = vfma(w22, p, TR[j-2]);
      }
      xa = xbv; xbv = xc;
    }
  }

  // horizontal combine: out[c0] = TL[c0-1]+TC[c0]+TR[c0+1];
  //                     out[c0+1] = TL[c0]+TC[c0+1]+TR[c0+2]
  v2f acc[RSTRIP];
#pragma unroll
  for (int r = 0; r < RSTRIP; ++r) {
    float pl = bperm(a_up, TL[r].y);
    float pr = bperm(a_dn, TR[r].x);
    if (lane0)  pl = 0.f;
    if (lane63) pr = 0.f;
    v2f v;
    v.x = pl      + TC[r].x + TR[r].y;
    v.y = TL[r].x + TC[r].y + pr;
    acc[r] = v;
  }

  // reduce the four i-quarters through LDS (lane-major; b64 2-way is free)
  __shared__ v2f red[3][RSTRIP][64];   // 12 KB
  if (iq != 0) {
#pragma unroll
    for (int r = 0; r < RSTRIP; ++r) red[iq - 1][r][lane] = acc[r];
  }
  __syncthreads();
  if (iq == 0) {
    float* yb = y + (((size_t)b * 32 + o) * 128 + r0) * 128 + c0;
#pragma unroll
    for (int r = 0; r < RSTRIP; ++r) {
      const v2f v = acc[r] + red[0][r][lane] + red[1][r][lane] + red[2][r][lane];
      *(v2f*)(yb + (size_t)r * 128) = v;
    }
  }
}

__global__ __launch_bounds__(256) void mix1x1(
    const float* __restrict__ y,    // (B, O, H*W)
    const float* __restrict__ fw,   // (O_out, O_in)
    float* __restrict__ out)        // (B, O, H*W)
{
  const int px = blockIdx.x * 256 + threadIdx.x;  // 0..16383
  const int b  = blockIdx.y;
  const float* yb = y + (size_t)b * 32 * 16384 + px;
  float v[32];
#pragma unroll
  for (int o = 0; o < 32; ++o) v[o] = yb[(size_t)o * 16384];
  float* ob = out + (size_t)b * 32 * 16384 + px;
#pragma unroll
  for (int p = 0; p < 32; ++p) {
    float a = 0.f;
#pragma unroll
    for (int o = 0; o < 32; ++o) a = fmaf(fw[p * 32 + o], v[o], a);
    ob[(size_t)p * 16384] = a;
  }
}

extern "C" void kernel_launch(void* const* d_in, const int* in_sizes, int n_in,
                              void* d_out, int out_size, void* d_ws, size_t ws_size,
                              hipStream_t stream) {
  const float* x     = (const float*)d_in[0];
  const float* scale = (const float*)d_in[1];
  const float* trans = (const float*)d_in[2];
  const float* wconv = (const float*)d_in[3];
  const float* fw    = (const float*)d_in[4];
  float* out = (float*)d_out;
  float* y   = (float*)d_ws;   // 4*32*128*128 floats = 8.39 MB

  const float mhc = (float)(2.0 / (sqrt(3.0) * pow(M_PI, 0.25)));

  dim3 g1(128 / RSTRIP, 32, 4);  // (strips, o, b) = 2048 blocks x 256 thr
  wavelet_grouped_conv<<<g1, 256, 0, stream>>>(x, scale, trans, wconv, y, mhc);

  dim3 g2(16384 / 256, 4);       // (pixel tiles, b)
  mix1x1<<<g2, 256, 0, stream>>>(y, fw, out);
}